// Round 8
// baseline (1167.221 us; speedup 1.0000x reference)
//
#include <hip/hip_runtime.h>

#define HIDDEN 2048
#define HEADS 16
#define HDIM 128
#define BQ 8
#define QLEN 1024
#define KVLEN 4096
#define MROWS (BQ * QLEN)  // 8192

typedef __bf16 bf16x8 __attribute__((ext_vector_type(8)));
typedef float f32x4 __attribute__((ext_vector_type(4)));
typedef unsigned short u16;
typedef u16 u16x8 __attribute__((ext_vector_type(8)));
typedef float f32x8v __attribute__((ext_vector_type(8)));

// fp32 -> bf16 bits, round-to-nearest-even
__device__ __forceinline__ u16 f2bf(float f) {
  union { float f; unsigned u; } v; v.f = f;
  unsigned r = (v.u + 0x7FFFu + ((v.u >> 16) & 1u)) >> 16;
  return (u16)r;
}

// async global->LDS, 16B per lane; LDS dest = wave-uniform base + lane*16
__device__ __forceinline__ void async_ld16(const void* g, void* l) {
  __builtin_amdgcn_global_load_lds(
      (const __attribute__((address_space(1))) void*)g,
      (__attribute__((address_space(3))) void*)l, 16, 0, 0);
}

// fp32 -> bf16 narrowing copy (inputs are fp32 per reference; output ws is bf16)
__global__ void convert_bf16(const float* __restrict__ src, u16* __restrict__ dst,
                             long n) {
  long base = ((long)blockIdx.x * blockDim.x + threadIdx.x) * 8;
  long stride = (long)gridDim.x * blockDim.x * 8;
  for (long i = base; i < n; i += stride) {
    f32x8v s = *(const f32x8v*)(src + i);
    u16x8 o;
#pragma unroll
    for (int j = 0; j < 8; j++) o[j] = f2bf(s[j]);
    *(u16x8*)(dst + i) = o;
  }
}

// C[M][N] = A[M][K] @ Bt[N][K]^T  (bf16 in, fp32 accum; out bf16 or fp32 per flag)
// 128x128 tile, 4 waves (2x2), each wave 64x64 = 4x4 frags of 16x16x32 MFMA.
__global__ __launch_bounds__(256) void gemm_bt(
    const u16* __restrict__ A, const u16* __restrict__ Bt, void* __restrict__ C,
    int M, int N, int K, int outf) {
  __shared__ __align__(16) u16 Asm[4 * 128 * 8];
  __shared__ __align__(16) u16 Bsm[4 * 128 * 8];
  const int tid = threadIdx.x;
  const int wid = tid >> 6, lane = tid & 63;
  const int quad = lane >> 4, l15 = lane & 15;
  const int wm = wid >> 1, wn = wid & 1;
  const int row0 = blockIdx.y * 128;
  const int col0 = blockIdx.x * 128;

  f32x4 acc[4][4];
#pragma unroll
  for (int i = 0; i < 4; i++)
#pragma unroll
    for (int j = 0; j < 4; j++) acc[i][j] = (f32x4){0.f, 0.f, 0.f, 0.f};

  for (int k0 = 0; k0 < K; k0 += 32) {
    __syncthreads();  // prev iter's ds_reads done before overwrite
#pragma unroll
    for (int i = 0; i < 4; i++) {
      int seg = wid + 4 * i;          // 0..15
      int isB = seg >> 3;
      int s = seg & 7;
      int q = s >> 1, hv = s & 1;     // k-quad, m-half
      const u16* gsrc = isB ? Bt : A;
      int grow = (isB ? col0 : row0) + hv * 64 + lane;
      const u16* g = gsrc + (size_t)grow * K + (k0 + q * 8);
      u16* l = (isB ? Bsm : Asm) + (q * 128 + hv * 64) * 8;  // wave-uniform
      async_ld16(g, l);
    }
    __syncthreads();  // drains vmcnt -> LDS ready
    bf16x8 af[4], bfr[4];
#pragma unroll
    for (int mt = 0; mt < 4; mt++)
      af[mt] = *(const bf16x8*)(Asm + (quad * 128 + wm * 64 + mt * 16 + l15) * 8);
#pragma unroll
    for (int nt = 0; nt < 4; nt++)
      bfr[nt] = *(const bf16x8*)(Bsm + (quad * 128 + wn * 64 + nt * 16 + l15) * 8);
#pragma unroll
    for (int mt = 0; mt < 4; mt++)
#pragma unroll
      for (int nt = 0; nt < 4; nt++)
        acc[mt][nt] = __builtin_amdgcn_mfma_f32_16x16x32_bf16(af[mt], bfr[nt], acc[mt][nt], 0, 0, 0);
  }

#pragma unroll
  for (int mt = 0; mt < 4; mt++)
#pragma unroll
    for (int r = 0; r < 4; r++) {
      int row = row0 + wm * 64 + mt * 16 + quad * 4 + r;
#pragma unroll
      for (int nt = 0; nt < 4; nt++) {
        int col = col0 + wn * 64 + nt * 16 + l15;
        if (outf) {
          ((float*)C)[(size_t)row * N + col] = acc[mt][nt][r];   // fp32 out (d_out)
        } else {
          ((u16*)C)[(size_t)row * N + col] = f2bf(acc[mt][nt][r]);  // bf16 ws
        }
      }
    }
}

// Flash attention: block = (qtile, head, batch); 256 thr = 4 waves, wave owns 32 q rows.
__global__ __launch_bounds__(256, 2) void attn(
    const u16* __restrict__ Q,   // [MROWS][HIDDEN] bf16
    const u16* __restrict__ Kv,  // [KVLEN][HIDDEN] bf16
    const u16* __restrict__ Vv,  // [KVLEN][HIDDEN] bf16
    u16* __restrict__ O) {       // [MROWS][HIDDEN] bf16
  __shared__ __align__(16) u16 KVb[128 * 136];
  __shared__ __align__(16) u16 Pb[128 * 136];
  const int tid = threadIdx.x;
  const int wid = tid >> 6, lane = tid & 63;
  const int quad = lane >> 4, l15 = lane & 15;
  const int qt = blockIdx.x, h = blockIdx.y, b = blockIdx.z;
  const int qrow0 = b * QLEN + qt * 128;
  const int hcol = h * HDIM;
  const float cexp = 0.08838834764831845f * 1.4426950408889634f;  // SCALE*log2(e)

  bf16x8 qf[2][4];
#pragma unroll
  for (int mt = 0; mt < 2; mt++)
#pragma unroll
    for (int ks = 0; ks < 4; ks++) {
      int row = qrow0 + wid * 32 + mt * 16 + l15;
      qf[mt][ks] = *(const bf16x8*)(Q + (size_t)row * HIDDEN + hcol + ks * 32 + quad * 8);
    }

  f32x4 o[2][8];
#pragma unroll
  for (int mt = 0; mt < 2; mt++)
#pragma unroll
    for (int dt = 0; dt < 8; dt++) o[mt][dt] = (f32x4){0.f, 0.f, 0.f, 0.f};
  float mrun[2][4], lrun[2][4];
#pragma unroll
  for (int mt = 0; mt < 2; mt++)
#pragma unroll
    for (int r = 0; r < 4; r++) { mrun[mt][r] = -INFINITY; lrun[mt][r] = 0.f; }

  for (int kv0 = 0; kv0 < KVLEN; kv0 += 128) {
    __syncthreads();  // (a) prev PV reads done
#pragma unroll
    for (int i = 0; i < 8; i++) {
      int seg = wid + 4 * i;        // 0..31
      int ch = seg >> 1, sh = seg & 1;
      int kvr = kv0 + sh * 64 + lane;
      const u16* g = Kv + (size_t)kvr * HIDDEN + hcol + ch * 8;
      u16* l = KVb + (ch * 128 + sh * 64) * 8;  // wave-uniform
      async_ld16(g, l);
    }
    __syncthreads();  // (b) K ready

    f32x4 s[2][8];
#pragma unroll
    for (int mt = 0; mt < 2; mt++)
#pragma unroll
      for (int nt = 0; nt < 8; nt++) s[mt][nt] = (f32x4){0.f, 0.f, 0.f, 0.f};
#pragma unroll
    for (int ks = 0; ks < 4; ks++) {
      bf16x8 kf[8];
#pragma unroll
      for (int nt = 0; nt < 8; nt++)
        kf[nt] = *(const bf16x8*)(KVb + ((ks * 4 + quad) * 128 + nt * 16 + l15) * 8);
#pragma unroll
      for (int mt = 0; mt < 2; mt++)
#pragma unroll
        for (int nt = 0; nt < 8; nt++)
          s[mt][nt] = __builtin_amdgcn_mfma_f32_16x16x32_bf16(qf[mt][ks], kf[nt], s[mt][nt], 0, 0, 0);
    }

#pragma unroll
    for (int mt = 0; mt < 2; mt++) {
#pragma unroll
      for (int r = 0; r < 4; r++) {
        float mx = s[mt][0][r];
#pragma unroll
        for (int nt = 1; nt < 8; nt++) mx = fmaxf(mx, s[mt][nt][r]);
#pragma unroll
        for (int off = 1; off < 16; off <<= 1) mx = fmaxf(mx, __shfl_xor(mx, off, 64));
        float mn = fmaxf(mrun[mt][r], mx);
        float al = __builtin_amdgcn_exp2f((mrun[mt][r] - mn) * cexp);
        mrun[mt][r] = mn;
        float mc = mn * cexp;
        float ps = 0.f;
#pragma unroll
        for (int nt = 0; nt < 8; nt++) {
          float p = __builtin_amdgcn_exp2f(s[mt][nt][r] * cexp - mc);
          s[mt][nt][r] = p;
          ps += p;
        }
#pragma unroll
        for (int off = 1; off < 16; off <<= 1) ps += __shfl_xor(ps, off, 64);
        lrun[mt][r] = lrun[mt][r] * al + ps;
#pragma unroll
        for (int dt = 0; dt < 8; dt++) o[mt][dt][r] *= al;
      }
    }

#pragma unroll
    for (int mt = 0; mt < 2; mt++)
#pragma unroll
      for (int nt = 0; nt < 8; nt++)
#pragma unroll
        for (int r = 0; r < 4; r++) {
          int prow = wid * 32 + mt * 16 + quad * 4 + r;
          Pb[prow * 136 + nt * 16 + l15] = f2bf(s[mt][nt][r]);
        }
    __syncthreads();  // (c) K reads + P writes done

    {
      int d = tid & 127, hf = tid >> 7;
#pragma unroll
      for (int kg = hf; kg < 16; kg += 2) {
        u16x8 v;
#pragma unroll
        for (int j = 0; j < 8; j++)
          v[j] = Vv[(size_t)(kv0 + kg * 8 + j) * HIDDEN + hcol + d];
        *(u16x8*)(KVb + d * 136 + kg * 8) = v;
      }
    }
    __syncthreads();  // (d) V^T ready

#pragma unroll
    for (int ks = 0; ks < 4; ks++) {
      bf16x8 pf[2], vf[8];
#pragma unroll
      for (int mt = 0; mt < 2; mt++)
        pf[mt] = *(const bf16x8*)(Pb + (wid * 32 + mt * 16 + l15) * 136 + ks * 32 + quad * 8);
#pragma unroll
      for (int dt = 0; dt < 8; dt++)
        vf[dt] = *(const bf16x8*)(KVb + (dt * 16 + l15) * 136 + ks * 32 + quad * 8);
#pragma unroll
      for (int mt = 0; mt < 2; mt++)
#pragma unroll
        for (int dt = 0; dt < 8; dt++)
          o[mt][dt] = __builtin_amdgcn_mfma_f32_16x16x32_bf16(pf[mt], vf[dt], o[mt][dt], 0, 0, 0);
    }
  }

#pragma unroll
  for (int mt = 0; mt < 2; mt++)
#pragma unroll
    for (int r = 0; r < 4; r++) {
      float inv = 1.0f / lrun[mt][r];
      int row = qrow0 + wid * 32 + mt * 16 + quad * 4 + r;
#pragma unroll
      for (int dt = 0; dt < 8; dt++) {
        int col = hcol + dt * 16 + l15;
        O[(size_t)row * HIDDEN + col] = f2bf(o[mt][dt][r] * inv);
      }
    }
}

extern "C" void kernel_launch(void* const* d_in, const int* in_sizes, int n_in,
                              void* d_out, int out_size, void* d_ws, size_t ws_size,
                              hipStream_t stream) {
  // Inputs: fp32, documented dict order (r2/r3/r4 evidence vindicates this wiring).
  const float* query = (const float*)d_in[0];
  const float* kv_k  = (const float*)d_in[1];
  const float* kv_v  = (const float*)d_in[2];
  const float* Wq    = (const float*)d_in[3];
  const float* Wo    = (const float*)d_in[4];
  // Output: fp32 (reference returns float32) — THE round-8 fix.
  float* out = (float*)d_out;

  const long NQ = (long)MROWS * HIDDEN;   // 16.78M
  const long NK = (long)KVLEN * HIDDEN;   // 8.39M
  const long NW = (long)HIDDEN * HIDDEN;  // 4.19M

  dim3 blk(256);

  // ws (u16): [convQ NQ][convK NK][convV NK][convWq NW][convWo NW][Qws NQ]; Ows aliases convQ.
  u16* convQ  = (u16*)d_ws;
  u16* convK  = convQ + NQ;
  u16* convV  = convK + NK;
  u16* convWq = convV + NK;
  u16* convWo = convWq + NW;
  u16* Qws    = convWo + NW;
  u16* Ows    = convQ;  // convQ dead after gemm1

  convert_bf16<<<dim3((NQ / 8 + 255) / 256), blk, 0, stream>>>(query, convQ,  NQ);
  convert_bf16<<<dim3((NK / 8 + 255) / 256), blk, 0, stream>>>(kv_k,  convK,  NK);
  convert_bf16<<<dim3((NK / 8 + 255) / 256), blk, 0, stream>>>(kv_v,  convV,  NK);
  convert_bf16<<<dim3((NW / 8 + 255) / 256), blk, 0, stream>>>(Wq,    convWq, NW);
  convert_bf16<<<dim3((NW / 8 + 255) / 256), blk, 0, stream>>>(Wo,    convWo, NW);

  gemm_bt<<<dim3(HIDDEN / 128, MROWS / 128), blk, 0, stream>>>(convQ, convWq, Qws, MROWS, HIDDEN, HIDDEN, 0);
  attn<<<dim3(QLEN / 128, HEADS, BQ), blk, 0, stream>>>(Qws, convK, convV, Ows);
  gemm_bt<<<dim3(HIDDEN / 128, MROWS / 128), blk, 0, stream>>>(Ows, convWo, out, MROWS, HIDDEN, HIDDEN, 1);
}